// Round 4
// baseline (1685.559 us; speedup 1.0000x reference)
//
#include <hip/hip_runtime.h>

#define DEVI static __device__ __forceinline__

constexpr int B = 8;
constexpr int N0 = 4096;
constexpr int KNB = 64;

typedef float f32x2 __attribute__((ext_vector_type(2)));

// d2 exactly as numpy: ((dx*dx + dy*dy) + dz*dz), no FMA contraction.
DEVI float dist2f(float ax, float ay, float az, float bx, float by, float bz) {
#pragma clang fp contract(off)
  float dx = ax - bx;
  float dy = ay - by;
  float dz = az - bz;
  return (dx * dx + dy * dy) + dz * dz;
}
// packed-pair version; same per-component rounding (mul/add only, no contract)
DEVI f32x2 dist2v(f32x2 ax, f32x2 ay, f32x2 az, float bx, float by, float bz) {
#pragma clang fp contract(off)
  f32x2 dx = ax - bx;
  f32x2 dy = ay - by;
  f32x2 dz = az - bz;
  return (dx * dx + dy * dy) + dz * dz;
}

// argmin key: min d wins, ties -> lowest index (radius overflow path)
DEVI unsigned long long packMinKey(float v, int i) {
  return ((unsigned long long)__float_as_uint(v) << 32) | (unsigned int)i;
}

// ---- DPP-based wave-64 reductions (VALU pipe, no LDS round-trips) ----
// Canonical GCN sequence: row_shr:1/2/4/8 then row_bcast:15 (rows 1,3) and
// row_bcast:31 (rows 2,3); total lands in lane 63. old = self, bound_ctrl off
// -> masked/shifted-in lanes keep their own value (no-op in max/min combine).
template <int CTRL, int RM, bool MAXR>
DEVI unsigned long long dppCombine(unsigned long long k) {
  unsigned int lo = (unsigned int)k, hi = (unsigned int)(k >> 32);
  unsigned int mlo = (unsigned int)__builtin_amdgcn_update_dpp(
      (int)lo, (int)lo, CTRL, RM, 0xf, false);
  unsigned int mhi = (unsigned int)__builtin_amdgcn_update_dpp(
      (int)hi, (int)hi, CTRL, RM, 0xf, false);
  unsigned long long o = ((unsigned long long)mhi << 32) | mlo;
  if (MAXR) return (k > o) ? k : o;
  return (k < o) ? k : o;
}
template <bool MAXR>
DEVI unsigned long long waveReduceU64(unsigned long long k) {
  k = dppCombine<0x111, 0xf, MAXR>(k);  // row_shr:1
  k = dppCombine<0x112, 0xf, MAXR>(k);  // row_shr:2
  k = dppCombine<0x114, 0xf, MAXR>(k);  // row_shr:4
  k = dppCombine<0x118, 0xf, MAXR>(k);  // row_shr:8
  k = dppCombine<0x142, 0xa, MAXR>(k);  // row_bcast:15 -> rows 1,3
  k = dppCombine<0x143, 0xc, MAXR>(k);  // row_bcast:31 -> rows 2,3
  unsigned int lo = (unsigned int)__builtin_amdgcn_readlane((int)(unsigned int)k, 63);
  unsigned int hi =
      (unsigned int)__builtin_amdgcn_readlane((int)(unsigned int)(k >> 32), 63);
  return ((unsigned long long)hi << 32) | lo;
}

// f32 max / u32 min wave reductions (cheap: 2 inst per level)
template <int CTRL, int RM>
DEVI float dppMaxF32(float v) {
  int o = __builtin_amdgcn_update_dpp(__float_as_int(v), __float_as_int(v),
                                      CTRL, RM, 0xf, false);
  return fmaxf(v, __int_as_float(o));
}
DEVI float waveMaxF32(float v) {
  v = dppMaxF32<0x111, 0xf>(v);
  v = dppMaxF32<0x112, 0xf>(v);
  v = dppMaxF32<0x114, 0xf>(v);
  v = dppMaxF32<0x118, 0xf>(v);
  v = dppMaxF32<0x142, 0xa>(v);
  v = dppMaxF32<0x143, 0xc>(v);
  return __int_as_float(__builtin_amdgcn_readlane(__float_as_int(v), 63));
}
template <int CTRL, int RM>
DEVI unsigned dppMinU32(unsigned v) {
  int o = __builtin_amdgcn_update_dpp((int)v, (int)v, CTRL, RM, 0xf, false);
  unsigned ov = (unsigned)o;
  return v < ov ? v : ov;
}
DEVI unsigned waveMinU32(unsigned v) {
  v = dppMinU32<0x111, 0xf>(v);
  v = dppMinU32<0x112, 0xf>(v);
  v = dppMinU32<0x114, 0xf>(v);
  v = dppMinU32<0x118, 0xf>(v);
  v = dppMinU32<0x142, 0xa>(v);
  v = dppMinU32<0x143, 0xc>(v);
  return (unsigned)__builtin_amdgcn_readlane((int)v, 63);
}

// ---------------- embedding + point_id_emb ----------------
__global__ void __launch_bounds__(256) x0_kernel(const int* __restrict__ feat,
                                                 const float* __restrict__ emb,
                                                 const float* __restrict__ pid,
                                                 float* __restrict__ x0) {
  int gid = blockIdx.x * 256 + threadIdx.x;  // over B*N0*32
  if (gid >= B * N0 * 32) return;
  int c = gid & 31;
  int bn = gid >> 5;
  int n = bn & (N0 - 1);
  int f = feat[bn];
  float v = emb[f * 32 + c];
  if (n < 1024) v += pid[n * 32 + c];
  x0[gid] = v;
}

// ---------------- farthest point sampling (VALU-throughput-optimized) ------
// Per iteration (2 phases):
//   value: lane fmax tree -> f32 DPP wave max -> cross-wave via LDS (bar 1)
//   index: per-lane eq-bitmask + ctz -> u32 DPP wave min -> LDS (bar 2)
// Distance update in packed float2 (v_pk_add/mul_f32), contract off.
// Selection semantics identical to jnp.argmax (ties -> lowest index).
template <int NPTS, int M, int BLK>
__global__ void __launch_bounds__(BLK) fps_kernel(const float* __restrict__ pos,
                                                  float* __restrict__ pos_out) {
  constexpr int EPT = NPTS / BLK;
  constexpr int EP2 = EPT / 2;
  constexpr int NW = BLK / 64;
  __shared__ float4 posl[NPTS];
  __shared__ float redv[NW < 2 ? 2 : NW];
  __shared__ unsigned redi[NW < 2 ? 2 : NW];
  const int b = blockIdx.x;
  const int t = threadIdx.x;
  const float* pb = pos + (size_t)b * NPTS * 3;
  f32x2 px[EP2], py[EP2], pz[EP2], d[EP2];
#pragma unroll
  for (int e = 0; e < EP2; ++e) {
    int i0 = t + (2 * e) * BLK;
    int i1 = t + (2 * e + 1) * BLK;
    float x0 = pb[i0 * 3 + 0], y0 = pb[i0 * 3 + 1], z0 = pb[i0 * 3 + 2];
    float x1 = pb[i1 * 3 + 0], y1 = pb[i1 * 3 + 1], z1 = pb[i1 * 3 + 2];
    px[e] = (f32x2){x0, x1};
    py[e] = (f32x2){y0, y1};
    pz[e] = (f32x2){z0, z1};
    posl[i0] = make_float4(x0, y0, z0, 0.f);
    posl[i1] = make_float4(x1, y1, z1, 0.f);
  }
  float sx = pb[0], sy = pb[1], sz = pb[2];
  if (t == 0) {
    pos_out[(size_t)(b * M) * 3 + 0] = sx;
    pos_out[(size_t)(b * M) * 3 + 1] = sy;
    pos_out[(size_t)(b * M) * 3 + 2] = sz;
  }
#pragma unroll
  for (int e = 0; e < EP2; ++e) d[e] = dist2v(px[e], py[e], pz[e], sx, sy, sz);

  for (int it = 1; it < M; ++it) {
    // ---- phase 1: max distance value ----
    float lm = fmaxf(d[0].x, d[0].y);
#pragma unroll
    for (int e = 1; e < EP2; ++e) lm = fmaxf(lm, fmaxf(d[e].x, d[e].y));
    lm = waveMaxF32(lm);
    float vstar;
    if constexpr (NW > 1) {
      if ((t & 63) == 0) redv[t >> 6] = lm;
      __syncthreads();
      vstar = redv[0];
#pragma unroll
      for (int w = 1; w < NW; ++w) vstar = fmaxf(vstar, redv[w]);
    } else {
      vstar = lm;
    }
    // ---- phase 2: lowest index attaining vstar ----
    unsigned mask = 0u;
#pragma unroll
    for (int e = 0; e < EP2; ++e) {
      mask |= (d[e].x == vstar) ? (1u << (2 * e)) : 0u;
      mask |= (d[e].y == vstar) ? (1u << (2 * e + 1)) : 0u;
    }
    // in-lane lowest bit = lowest global idx (idx = t + e*BLK monotone in e)
    unsigned cand =
        mask ? (unsigned)(t + __builtin_ctz(mask) * BLK) : 0xffffffffu;
    cand = waveMinU32(cand);
    unsigned sel;
    if constexpr (NW > 1) {
      if ((t & 63) == 0) redi[t >> 6] = cand;
      __syncthreads();
      sel = redi[0];
#pragma unroll
      for (int w = 1; w < NW; ++w) sel = sel < redi[w] ? sel : redi[w];
    } else {
      sel = cand;
    }
    float4 sp = posl[sel];  // LDS broadcast
    if (t == 0) {
      pos_out[(size_t)(b * M + it) * 3 + 0] = sp.x;
      pos_out[(size_t)(b * M + it) * 3 + 1] = sp.y;
      pos_out[(size_t)(b * M + it) * 3 + 2] = sp.z;
    }
#pragma unroll
    for (int e = 0; e < EP2; ++e) {
      f32x2 nd = dist2v(px[e], py[e], pz[e], sp.x, sp.y, sp.z);
      d[e].x = fminf(d[e].x, nd.x);
      d[e].y = fminf(d[e].y, nd.y);
    }
  }
}

// ---------------- radius neighbors (<=64 nearest within r) ----------------
template <int NPTS, int M>
__global__ void __launch_bounds__(256) radius_kernel(const float* __restrict__ pos,
                                                     const float* __restrict__ pos_s,
                                                     float r2,
                                                     int* __restrict__ nbr,
                                                     int* __restrict__ cnt) {
  __shared__ float d2s[NPTS];
  __shared__ unsigned long long red[4];
  __shared__ int ctr;
  const float INFV = __builtin_inff();
  const int blk = blockIdx.x;
  const int t = threadIdx.x;
  const int b = blk / M;
  const float* pb = pos + (size_t)b * NPTS * 3;
  const float cx = pos_s[(size_t)blk * 3 + 0];
  const float cy = pos_s[(size_t)blk * 3 + 1];
  const float cz = pos_s[(size_t)blk * 3 + 2];
  if (t == 0) ctr = 0;
  __syncthreads();
  for (int j = t; j < NPTS; j += 256) {
    float d2 = dist2f(pb[j * 3 + 0], pb[j * 3 + 1], pb[j * 3 + 2], cx, cy, cz);
    d2s[j] = (d2 <= r2) ? d2 : INFV;
  }
  __syncthreads();
  for (int j = t; j < NPTS; j += 256) {
    if (d2s[j] < INFV) {
      int p = atomicAdd(&ctr, 1);
      if (p < KNB) nbr[(size_t)blk * KNB + p] = j;
    }
  }
  __syncthreads();
  const int c = ctr;
  if (c <= KNB) {
    if (t == 0) cnt[blk] = c;
    return;
  }
  // overflow: exact 64-nearest, ties -> lower index (matches lax.top_k)
  for (int k = 0; k < KNB; ++k) {
    unsigned long long lk = ~0ULL;
    for (int j = t; j < NPTS; j += 256) {
      unsigned long long kk = packMinKey(d2s[j], j);
      lk = (lk < kk) ? lk : kk;
    }
    lk = waveReduceU64<false>(lk);
    if ((t & 63) == 0) red[t >> 6] = lk;
    __syncthreads();
#pragma unroll
    for (int w = 0; w < 4; ++w) {
      unsigned long long o = red[w];
      lk = (lk < o) ? lk : o;
    }
    int idx = (int)(unsigned int)(lk & 0xffffffffULL);
    if (t == 0) {
      nbr[(size_t)blk * KNB + k] = idx;
      d2s[idx] = INFV;
    }
    __syncthreads();
  }
  if (t == 0) cnt[blk] = KNB;
}

// ---------------- stage 1 conv: 35 -> 64 -> 64 -> 64, max over nbrs ----------------
__global__ void __launch_bounds__(64) conv1_kernel(
    const float* __restrict__ x0, const float* __restrict__ pos,
    const float* __restrict__ pos_s, const int* __restrict__ nbr,
    const int* __restrict__ cntp,
    const float* __restrict__ w0, const float* __restrict__ b0,
    const float* __restrict__ w1, const float* __restrict__ b1,
    const float* __restrict__ w2, const float* __restrict__ b2,
    float* __restrict__ x1) {
  __shared__ float ins[35];
  __shared__ float h[64];
  const int blk = blockIdx.x;  // B*1024
  const int t = threadIdx.x;
  const int b = blk >> 10;
  const int c = cntp[blk];
  const float cx = pos_s[(size_t)blk * 3 + 0];
  const float cy = pos_s[(size_t)blk * 3 + 1];
  const float cz = pos_s[(size_t)blk * 3 + 2];
  float best = -__builtin_inff();
  for (int r = 0; r < c; ++r) {
    int j = nbr[(size_t)blk * KNB + r];
    if (t < 32) {
      ins[t] = x0[((size_t)(b * N0) + j) * 32 + t];
    } else if (t < 35) {
      float pv = pos[((size_t)(b * N0) + j) * 3 + (t - 32)];
      float cv = (t == 32) ? cx : (t == 33) ? cy : cz;
      ins[t] = pv - cv;
    }
    __syncthreads();
    float v = b0[t];
#pragma unroll
    for (int i = 0; i < 35; ++i) v = fmaf(ins[i], w0[i * 64 + t], v);
    v = fmaxf(v, 0.f);
    h[t] = v;
    __syncthreads();
    float v2 = b1[t];
#pragma unroll
    for (int i = 0; i < 64; ++i) v2 = fmaf(h[i], w1[i * 64 + t], v2);
    v2 = fmaxf(v2, 0.f);
    __syncthreads();
    h[t] = v2;
    __syncthreads();
    float v3 = b2[t];
#pragma unroll
    for (int i = 0; i < 64; ++i) v3 = fmaf(h[i], w2[i * 64 + t], v3);
    best = fmaxf(best, v3);
    __syncthreads();
  }
  x1[(size_t)blk * 64 + t] = best;
}

// ---------------- stage 2 conv: 67 -> 128 -> 128 -> 256, max over nbrs ----------------
__global__ void __launch_bounds__(256) conv2_kernel(
    const float* __restrict__ x1, const float* __restrict__ pos1,
    const float* __restrict__ pos2, const int* __restrict__ nbr,
    const int* __restrict__ cntp,
    const float* __restrict__ w0, const float* __restrict__ b0,
    const float* __restrict__ w1, const float* __restrict__ b1,
    const float* __restrict__ w2, const float* __restrict__ b2,
    float* __restrict__ x2) {
  __shared__ __attribute__((aligned(16))) float msg[64][68];
  __shared__ __attribute__((aligned(16))) float h[64][128];
  __shared__ float red[8][256];
  const int blk = blockIdx.x;  // B*256
  const int t = threadIdx.x;
  const int b = blk >> 8;
  const int c = cntp[blk];
  const float cx = pos2[(size_t)blk * 3 + 0];
  const float cy = pos2[(size_t)blk * 3 + 1];
  const float cz = pos2[(size_t)blk * 3 + 2];
  for (int idx = t; idx < 64 * 68; idx += 256) {
    int r = idx / 68;
    int k = idx - r * 68;
    float v = 0.f;
    if (r < c && k < 67) {
      int j = nbr[(size_t)blk * KNB + r];
      if (k < 64) {
        v = x1[((size_t)(b * 1024) + j) * 64 + k];
      } else {
        float pv = pos1[((size_t)(b * 1024) + j) * 3 + (k - 64)];
        v = pv - ((k == 64) ? cx : (k == 65) ? cy : cz);
      }
    }
    msg[r][k] = v;
  }
  __syncthreads();
  const int rg = t >> 5;  // 8 row-groups of 8 rows
  const int cg = t & 31;
  // L1: K=67 -> h[64][128]
  {
    float acc[8][4] = {};
    for (int i4 = 0; i4 < 16; ++i4) {
      float wv[4][4];
#pragma unroll
      for (int k = 0; k < 4; ++k) {
        float4 q = *(const float4*)&w0[(size_t)(i4 * 4 + k) * 128 + cg * 4];
        wv[k][0] = q.x; wv[k][1] = q.y; wv[k][2] = q.z; wv[k][3] = q.w;
      }
#pragma unroll
      for (int rr = 0; rr < 8; ++rr) {
        float4 aq = *(const float4*)&msg[rg * 8 + rr][i4 * 4];
        float a[4] = {aq.x, aq.y, aq.z, aq.w};
#pragma unroll
        for (int k = 0; k < 4; ++k)
#pragma unroll
          for (int cc = 0; cc < 4; ++cc)
            acc[rr][cc] = fmaf(a[k], wv[k][cc], acc[rr][cc]);
      }
    }
#pragma unroll
    for (int i = 64; i < 67; ++i) {
      float wv[4];
#pragma unroll
      for (int cc = 0; cc < 4; ++cc) wv[cc] = w0[(size_t)i * 128 + cg * 4 + cc];
#pragma unroll
      for (int rr = 0; rr < 8; ++rr) {
        float a = msg[rg * 8 + rr][i];
#pragma unroll
        for (int cc = 0; cc < 4; ++cc) acc[rr][cc] = fmaf(a, wv[cc], acc[rr][cc]);
      }
    }
#pragma unroll
    for (int rr = 0; rr < 8; ++rr)
#pragma unroll
      for (int cc = 0; cc < 4; ++cc)
        h[rg * 8 + rr][cg * 4 + cc] = fmaxf(acc[rr][cc] + b0[cg * 4 + cc], 0.f);
  }
  __syncthreads();
  // L2: K=128, in-place on h
  {
    float acc[8][4] = {};
    for (int i4 = 0; i4 < 32; ++i4) {
      float wv[4][4];
#pragma unroll
      for (int k = 0; k < 4; ++k) {
        float4 q = *(const float4*)&w1[(size_t)(i4 * 4 + k) * 128 + cg * 4];
        wv[k][0] = q.x; wv[k][1] = q.y; wv[k][2] = q.z; wv[k][3] = q.w;
      }
#pragma unroll
      for (int rr = 0; rr < 8; ++rr) {
        float4 aq = *(const float4*)&h[rg * 8 + rr][i4 * 4];
        float a[4] = {aq.x, aq.y, aq.z, aq.w};
#pragma unroll
        for (int k = 0; k < 4; ++k)
#pragma unroll
          for (int cc = 0; cc < 4; ++cc)
            acc[rr][cc] = fmaf(a[k], wv[k][cc], acc[rr][cc]);
      }
    }
    __syncthreads();  // all reads of h done before overwrite
#pragma unroll
    for (int rr = 0; rr < 8; ++rr)
#pragma unroll
      for (int cc = 0; cc < 4; ++cc)
        h[rg * 8 + rr][cg * 4 + cc] = fmaxf(acc[rr][cc] + b1[cg * 4 + cc], 0.f);
  }
  __syncthreads();
  // L3: K=128 -> 64x256, then masked max over rows
  {
    float acc[8][8] = {};
    for (int i4 = 0; i4 < 32; ++i4) {
      float wv[4][8];
#pragma unroll
      for (int k = 0; k < 4; ++k) {
        float4 q0 = *(const float4*)&w2[(size_t)(i4 * 4 + k) * 256 + cg * 8];
        float4 q1 = *(const float4*)&w2[(size_t)(i4 * 4 + k) * 256 + cg * 8 + 4];
        wv[k][0] = q0.x; wv[k][1] = q0.y; wv[k][2] = q0.z; wv[k][3] = q0.w;
        wv[k][4] = q1.x; wv[k][5] = q1.y; wv[k][6] = q1.z; wv[k][7] = q1.w;
      }
#pragma unroll
      for (int rr = 0; rr < 8; ++rr) {
        float4 aq = *(const float4*)&h[rg * 8 + rr][i4 * 4];
        float a[4] = {aq.x, aq.y, aq.z, aq.w};
#pragma unroll
        for (int k = 0; k < 4; ++k)
#pragma unroll
          for (int cc = 0; cc < 8; ++cc)
            acc[rr][cc] = fmaf(a[k], wv[k][cc], acc[rr][cc]);
      }
    }
    float mx[8];
#pragma unroll
    for (int cc = 0; cc < 8; ++cc) mx[cc] = -__builtin_inff();
#pragma unroll
    for (int rr = 0; rr < 8; ++rr) {
      if (rg * 8 + rr < c) {
#pragma unroll
        for (int cc = 0; cc < 8; ++cc)
          mx[cc] = fmaxf(mx[cc], acc[rr][cc] + b2[cg * 8 + cc]);
      }
    }
#pragma unroll
    for (int cc = 0; cc < 8; ++cc) red[rg][cg * 8 + cc] = mx[cc];
  }
  __syncthreads();
  {
    float v = red[0][t];
#pragma unroll
    for (int g = 1; g < 8; ++g) v = fmaxf(v, red[g][t]);
    x2[(size_t)blk * 256 + t] = v;
  }
}

// ---------------- stage 3 conv: 259 -> 256 -> 512 -> 512, max over nbrs ----------------
__global__ void __launch_bounds__(256) conv3_kernel(
    const float* __restrict__ x2, const float* __restrict__ pos2,
    const float* __restrict__ pos3, const int* __restrict__ nbr,
    const int* __restrict__ cntp,
    const float* __restrict__ w0, const float* __restrict__ b0,
    const float* __restrict__ w1, const float* __restrict__ b1,
    const float* __restrict__ w2, const float* __restrict__ b2,
    float* __restrict__ out) {
  __shared__ __attribute__((aligned(16))) float msg[16][260];
  __shared__ __attribute__((aligned(16))) float h[16][512];
  __shared__ float red[4][512];
  __shared__ float omax[512];
  const int blk = blockIdx.x;  // B*64
  const int t = threadIdx.x;
  const int b = blk >> 6;
  const int c = cntp[blk];
  const float cx = pos3[(size_t)blk * 3 + 0];
  const float cy = pos3[(size_t)blk * 3 + 1];
  const float cz = pos3[(size_t)blk * 3 + 2];
  omax[t] = -__builtin_inff();
  omax[t + 256] = -__builtin_inff();
  const int rg = t >> 6;  // 4 row-groups of 4 rows
  const int cg = t & 63;
  __syncthreads();
  for (int ch = 0; ch < 4; ++ch) {
    if (ch * 16 >= c) break;
    for (int idx = t; idx < 16 * 260; idx += 256) {
      int r = idx / 260;
      int k = idx - r * 260;
      int rglob = ch * 16 + r;
      float v = 0.f;
      if (rglob < c && k < 259) {
        int j = nbr[(size_t)blk * KNB + rglob];
        if (k < 256) {
          v = x2[((size_t)(b * 256) + j) * 256 + k];
        } else {
          float pv = pos2[((size_t)(b * 256) + j) * 3 + (k - 256)];
          v = pv - ((k == 256) ? cx : (k == 257) ? cy : cz);
        }
      }
      msg[r][k] = v;
    }
    __syncthreads();
    // L1: 16x256, K=259
    {
      float acc[4][4] = {};
      for (int i4 = 0; i4 < 64; ++i4) {
        float wv[4][4];
#pragma unroll
        for (int k = 0; k < 4; ++k) {
          float4 q = *(const float4*)&w0[(size_t)(i4 * 4 + k) * 256 + cg * 4];
          wv[k][0] = q.x; wv[k][1] = q.y; wv[k][2] = q.z; wv[k][3] = q.w;
        }
#pragma unroll
        for (int rr = 0; rr < 4; ++rr) {
          float4 aq = *(const float4*)&msg[rg * 4 + rr][i4 * 4];
          float a[4] = {aq.x, aq.y, aq.z, aq.w};
#pragma unroll
          for (int k = 0; k < 4; ++k)
#pragma unroll
            for (int cc = 0; cc < 4; ++cc)
              acc[rr][cc] = fmaf(a[k], wv[k][cc], acc[rr][cc]);
        }
      }
#pragma unroll
      for (int i = 256; i < 259; ++i) {
        float wv[4];
#pragma unroll
        for (int cc = 0; cc < 4; ++cc) wv[cc] = w0[(size_t)i * 256 + cg * 4 + cc];
#pragma unroll
        for (int rr = 0; rr < 4; ++rr) {
          float a = msg[rg * 4 + rr][i];
#pragma unroll
          for (int cc = 0; cc < 4; ++cc) acc[rr][cc] = fmaf(a, wv[cc], acc[rr][cc]);
        }
      }
#pragma unroll
      for (int rr = 0; rr < 4; ++rr)
#pragma unroll
        for (int cc = 0; cc < 4; ++cc)
          h[rg * 4 + rr][cg * 4 + cc] = fmaxf(acc[rr][cc] + b0[cg * 4 + cc], 0.f);
    }
    __syncthreads();
    // L2: 16x512, K=256, in-place on h (read cols 0..255, write 0..511)
    {
      float acc[4][8] = {};
      for (int i4 = 0; i4 < 64; ++i4) {
        float wv[4][8];
#pragma unroll
        for (int k = 0; k < 4; ++k) {
          float4 q0 = *(const float4*)&w1[(size_t)(i4 * 4 + k) * 512 + cg * 8];
          float4 q1 = *(const float4*)&w1[(size_t)(i4 * 4 + k) * 512 + cg * 8 + 4];
          wv[k][0] = q0.x; wv[k][1] = q0.y; wv[k][2] = q0.z; wv[k][3] = q0.w;
          wv[k][4] = q1.x; wv[k][5] = q1.y; wv[k][6] = q1.z; wv[k][7] = q1.w;
        }
#pragma unroll
        for (int rr = 0; rr < 4; ++rr) {
          float4 aq = *(const float4*)&h[rg * 4 + rr][i4 * 4];
          float a[4] = {aq.x, aq.y, aq.z, aq.w};
#pragma unroll
          for (int k = 0; k < 4; ++k)
#pragma unroll
            for (int cc = 0; cc < 8; ++cc)
              acc[rr][cc] = fmaf(a[k], wv[k][cc], acc[rr][cc]);
        }
      }
      __syncthreads();
#pragma unroll
      for (int rr = 0; rr < 4; ++rr)
#pragma unroll
        for (int cc = 0; cc < 8; ++cc)
          h[rg * 4 + rr][cg * 8 + cc] = fmaxf(acc[rr][cc] + b1[cg * 8 + cc], 0.f);
    }
    __syncthreads();
    // L3: 16x512, K=512, masked max
    {
      float acc[4][8] = {};
      for (int i4 = 0; i4 < 128; ++i4) {
        float wv[4][8];
#pragma unroll
        for (int k = 0; k < 4; ++k) {
          float4 q0 = *(const float4*)&w2[(size_t)(i4 * 4 + k) * 512 + cg * 8];
          float4 q1 = *(const float4*)&w2[(size_t)(i4 * 4 + k) * 512 + cg * 8 + 4];
          wv[k][0] = q0.x; wv[k][1] = q0.y; wv[k][2] = q0.z; wv[k][3] = q0.w;
          wv[k][4] = q1.x; wv[k][5] = q1.y; wv[k][6] = q1.z; wv[k][7] = q1.w;
        }
#pragma unroll
        for (int rr = 0; rr < 4; ++rr) {
          float4 aq = *(const float4*)&h[rg * 4 + rr][i4 * 4];
          float a[4] = {aq.x, aq.y, aq.z, aq.w};
#pragma unroll
          for (int k = 0; k < 4; ++k)
#pragma unroll
            for (int cc = 0; cc < 8; ++cc)
              acc[rr][cc] = fmaf(a[k], wv[k][cc], acc[rr][cc]);
        }
      }
      float mx[8];
#pragma unroll
      for (int cc = 0; cc < 8; ++cc) mx[cc] = -__builtin_inff();
#pragma unroll
      for (int rr = 0; rr < 4; ++rr) {
        if (ch * 16 + rg * 4 + rr < c) {
#pragma unroll
          for (int cc = 0; cc < 8; ++cc)
            mx[cc] = fmaxf(mx[cc], acc[rr][cc] + b2[cg * 8 + cc]);
        }
      }
#pragma unroll
      for (int cc = 0; cc < 8; ++cc) red[rg][cg * 8 + cc] = mx[cc];
    }
    __syncthreads();
    for (int k = t; k < 512; k += 256) {
      float v = omax[k];
#pragma unroll
      for (int g = 0; g < 4; ++g) v = fmaxf(v, red[g][k]);
      omax[k] = v;
    }
    __syncthreads();
  }
  out[(size_t)blk * 512 + t] = omax[t];
  out[(size_t)blk * 512 + t + 256] = omax[t + 256];
}

extern "C" void kernel_launch(void* const* d_in, const int* in_sizes, int n_in,
                              void* d_out, int out_size, void* d_ws, size_t ws_size,
                              hipStream_t stream) {
  const int* feat = (const int*)d_in[0];
  const float* pos = (const float*)d_in[1];
  const float* emb = (const float*)d_in[2];
  const float* pid = (const float*)d_in[3];
  const float* s1w0 = (const float*)d_in[4];
  const float* s1b0 = (const float*)d_in[5];
  const float* s1w1 = (const float*)d_in[6];
  const float* s1b1 = (const float*)d_in[7];
  const float* s1w2 = (const float*)d_in[8];
  const float* s1b2 = (const float*)d_in[9];
  const float* s2w0 = (const float*)d_in[10];
  const float* s2b0 = (const float*)d_in[11];
  const float* s2w1 = (const float*)d_in[12];
  const float* s2b1 = (const float*)d_in[13];
  const float* s2w2 = (const float*)d_in[14];
  const float* s2b2 = (const float*)d_in[15];
  const float* s3w0 = (const float*)d_in[16];
  const float* s3b0 = (const float*)d_in[17];
  const float* s3w1 = (const float*)d_in[18];
  const float* s3b1 = (const float*)d_in[19];
  const float* s3w2 = (const float*)d_in[20];
  const float* s3b2 = (const float*)d_in[21];
  (void)in_sizes; (void)n_in; (void)out_size; (void)ws_size;

  char* ws = (char*)d_ws;
  size_t off = 0;
  auto alloc = [&](size_t nbytes) {
    void* p = ws + off;
    off = (off + nbytes + 255) & ~(size_t)255;
    return p;
  };
  float* x0 = (float*)alloc((size_t)B * N0 * 32 * 4);
  float* pos1 = (float*)alloc((size_t)B * 1024 * 3 * 4);
  int* nbr1 = (int*)alloc((size_t)B * 1024 * KNB * 4);
  int* cnt1 = (int*)alloc((size_t)B * 1024 * 4);
  float* x1 = (float*)alloc((size_t)B * 1024 * 64 * 4);
  float* pos2 = (float*)alloc((size_t)B * 256 * 3 * 4);
  int* nbr2 = (int*)alloc((size_t)B * 256 * KNB * 4);
  int* cnt2 = (int*)alloc((size_t)B * 256 * 4);
  float* x2 = (float*)alloc((size_t)B * 256 * 256 * 4);
  int* nbr3 = (int*)alloc((size_t)B * 64 * KNB * 4);
  int* cnt3 = (int*)alloc((size_t)B * 64 * 4);

  float* xout = (float*)d_out;                 // (B,64,512)
  float* pos3 = xout + (size_t)B * 64 * 512;   // (B,64,3)

  const float r2a = (float)(0.05 * 0.05);
  const float r2b = (float)(0.3 * 0.3);
  const float r2c = (float)(0.5 * 0.5);

  x0_kernel<<<(B * N0 * 32 + 255) / 256, 256, 0, stream>>>(feat, emb, pid, x0);

  fps_kernel<4096, 1024, 512><<<B, 512, 0, stream>>>(pos, pos1);
  radius_kernel<4096, 1024><<<B * 1024, 256, 0, stream>>>(pos, pos1, r2a, nbr1, cnt1);
  conv1_kernel<<<B * 1024, 64, 0, stream>>>(x0, pos, pos1, nbr1, cnt1,
                                            s1w0, s1b0, s1w1, s1b1, s1w2, s1b2, x1);

  fps_kernel<1024, 256, 256><<<B, 256, 0, stream>>>(pos1, pos2);
  radius_kernel<1024, 256><<<B * 256, 256, 0, stream>>>(pos1, pos2, r2b, nbr2, cnt2);
  conv2_kernel<<<B * 256, 256, 0, stream>>>(x1, pos1, pos2, nbr2, cnt2,
                                            s2w0, s2b0, s2w1, s2b1, s2w2, s2b2, x2);

  fps_kernel<256, 64, 64><<<B, 64, 0, stream>>>(pos2, pos3);
  radius_kernel<256, 64><<<B * 64, 256, 0, stream>>>(pos2, pos3, r2c, nbr3, cnt3);
  conv3_kernel<<<B * 64, 256, 0, stream>>>(x2, pos2, pos3, nbr3, cnt3,
                                           s3w0, s3b0, s3w1, s3b1, s3w2, s3b2, xout);
}

// Round 5
// 1519.591 us; speedup vs baseline: 1.1092x; 1.1092x over previous
//
#include <hip/hip_runtime.h>

#define DEVI static __device__ __forceinline__

constexpr int B = 8;
constexpr int N0 = 4096;
constexpr int KNB = 64;

typedef float f32x2 __attribute__((ext_vector_type(2)));

// d2 exactly as numpy: ((dx*dx + dy*dy) + dz*dz), no FMA contraction.
DEVI float dist2f(float ax, float ay, float az, float bx, float by, float bz) {
#pragma clang fp contract(off)
  float dx = ax - bx;
  float dy = ay - by;
  float dz = az - bz;
  return (dx * dx + dy * dy) + dz * dz;
}
// packed-pair version; same per-component rounding (mul/add only, no contract)
DEVI f32x2 dist2v(f32x2 ax, f32x2 ay, f32x2 az, float bx, float by, float bz) {
#pragma clang fp contract(off)
  f32x2 dx = ax - bx;
  f32x2 dy = ay - by;
  f32x2 dz = az - bz;
  return (dx * dx + dy * dy) + dz * dz;
}

// ascending key: min (d2, idx) wins; d2>=0 so float bits are monotone
DEVI unsigned long long packMinKey(float v, int i) {
  return ((unsigned long long)__float_as_uint(v) << 32) | (unsigned int)i;
}

// f32 max / u32 min wave-64 reductions on the VALU pipe (DPP), result
// broadcast to all lanes via readlane(63).
template <int CTRL, int RM>
DEVI float dppMaxF32(float v) {
  int o = __builtin_amdgcn_update_dpp(__float_as_int(v), __float_as_int(v),
                                      CTRL, RM, 0xf, false);
  return fmaxf(v, __int_as_float(o));
}
DEVI float waveMaxF32(float v) {
  v = dppMaxF32<0x111, 0xf>(v);  // row_shr:1
  v = dppMaxF32<0x112, 0xf>(v);  // row_shr:2
  v = dppMaxF32<0x114, 0xf>(v);  // row_shr:4
  v = dppMaxF32<0x118, 0xf>(v);  // row_shr:8
  v = dppMaxF32<0x142, 0xa>(v);  // row_bcast:15 -> rows 1,3
  v = dppMaxF32<0x143, 0xc>(v);  // row_bcast:31 -> rows 2,3
  return __int_as_float(__builtin_amdgcn_readlane(__float_as_int(v), 63));
}
template <int CTRL, int RM>
DEVI unsigned dppMinU32(unsigned v) {
  int o = __builtin_amdgcn_update_dpp((int)v, (int)v, CTRL, RM, 0xf, false);
  unsigned ov = (unsigned)o;
  return v < ov ? v : ov;
}
DEVI unsigned waveMinU32(unsigned v) {
  v = dppMinU32<0x111, 0xf>(v);
  v = dppMinU32<0x112, 0xf>(v);
  v = dppMinU32<0x114, 0xf>(v);
  v = dppMinU32<0x118, 0xf>(v);
  v = dppMinU32<0x142, 0xa>(v);
  v = dppMinU32<0x143, 0xc>(v);
  return (unsigned)__builtin_amdgcn_readlane((int)v, 63);
}

// ---------------- embedding + point_id_emb ----------------
__global__ void __launch_bounds__(256) x0_kernel(const int* __restrict__ feat,
                                                 const float* __restrict__ emb,
                                                 const float* __restrict__ pid,
                                                 float* __restrict__ x0) {
  int gid = blockIdx.x * 256 + threadIdx.x;  // over B*N0*32
  if (gid >= B * N0 * 32) return;
  int c = gid & 31;
  int bn = gid >> 5;
  int n = bn & (N0 - 1);
  int f = feat[bn];
  float v = emb[f * 32 + c];
  if (n < 1024) v += pid[n * 32 + c];
  x0[gid] = v;
}

// ---------------- farthest point sampling ----------------
// BLK=256 -> 4 waves, 1 wave/SIMD (each instruction issued once per SIMD).
// Per iteration: pk-f32 distance state; in-wave f32-max DPP reduce; eq-mask
// u32-min DPP for the wave's lowest achieving index; wave leader packs one
// u64 key (maxbits<<32 | 0x7fffffff-idx) into double-buffered LDS; ONE
// barrier; 4-key max tree; posl[sel] float4 LDS broadcast; pk update.
// Selection semantics identical to jnp.argmax (ties -> lowest index).
template <int NPTS, int M, int BLK>
__global__ void __launch_bounds__(BLK) fps_kernel(const float* __restrict__ pos,
                                                  float* __restrict__ pos_out) {
  constexpr int EPT = NPTS / BLK;
  constexpr int EP2 = EPT / 2;
  constexpr int NW = BLK / 64;
  __shared__ float4 posl[NPTS];
  __shared__ alignas(16) unsigned long long redk[2][NW < 2 ? 2 : NW];
  const int b = blockIdx.x;
  const int t = threadIdx.x;
  const float* pb = pos + (size_t)b * NPTS * 3;
  f32x2 px[EP2], py[EP2], pz[EP2], d[EP2];
#pragma unroll
  for (int e = 0; e < EP2; ++e) {
    int i0 = t + (2 * e) * BLK;
    int i1 = t + (2 * e + 1) * BLK;
    float x0 = pb[i0 * 3 + 0], y0 = pb[i0 * 3 + 1], z0 = pb[i0 * 3 + 2];
    float x1 = pb[i1 * 3 + 0], y1 = pb[i1 * 3 + 1], z1 = pb[i1 * 3 + 2];
    px[e] = (f32x2){x0, x1};
    py[e] = (f32x2){y0, y1};
    pz[e] = (f32x2){z0, z1};
    posl[i0] = make_float4(x0, y0, z0, 0.f);
    posl[i1] = make_float4(x1, y1, z1, 0.f);
  }
  float sx = pb[0], sy = pb[1], sz = pb[2];
  if (t == 0) {
    pos_out[(size_t)(b * M) * 3 + 0] = sx;
    pos_out[(size_t)(b * M) * 3 + 1] = sy;
    pos_out[(size_t)(b * M) * 3 + 2] = sz;
  }
#pragma unroll
  for (int e = 0; e < EP2; ++e) d[e] = dist2v(px[e], py[e], pz[e], sx, sy, sz);

  for (int it = 1; it < M; ++it) {
    // wave max value (exact fmax tree -> DPP -> uniform via readlane)
    float lm = fmaxf(d[0].x, d[0].y);
#pragma unroll
    for (int e = 1; e < EP2; ++e) lm = fmaxf(lm, fmaxf(d[e].x, d[e].y));
    const float vstar = waveMaxF32(lm);
    // wave's lowest index attaining vstar (>=1 lane matches within the wave)
    unsigned cand = 0xffffffffu;
#pragma unroll
    for (int e = 0; e < EP2; ++e) {
      unsigned c0 = (d[e].x == vstar) ? (unsigned)(t + (2 * e) * BLK) : 0xffffffffu;
      unsigned c1 = (d[e].y == vstar) ? (unsigned)(t + (2 * e + 1) * BLK) : 0xffffffffu;
      cand = cand < c0 ? cand : c0;
      cand = cand < c1 ? cand : c1;
    }
    cand = waveMinU32(cand);
    unsigned sel;
    if constexpr (NW > 1) {
      if ((t & 63) == 0) {
        unsigned long long key =
            ((unsigned long long)__float_as_uint(vstar) << 32) |
            (unsigned)(0x7fffffffu - cand);
        redk[it & 1][t >> 6] = key;
      }
      __syncthreads();  // double-buffered -> single barrier is race-free
      unsigned long long kk = redk[it & 1][0];
#pragma unroll
      for (int w = 1; w < NW; ++w) {
        unsigned long long o = redk[it & 1][w];
        kk = (kk > o) ? kk : o;
      }
      sel = 0x7fffffffu - (unsigned)(kk & 0xffffffffULL);
    } else {
      sel = cand;
    }
    float4 sp = posl[sel];  // LDS broadcast
    if (t == 0) {
      pos_out[(size_t)(b * M + it) * 3 + 0] = sp.x;
      pos_out[(size_t)(b * M + it) * 3 + 1] = sp.y;
      pos_out[(size_t)(b * M + it) * 3 + 2] = sp.z;
    }
#pragma unroll
    for (int e = 0; e < EP2; ++e) {
      f32x2 nd = dist2v(px[e], py[e], pz[e], sp.x, sp.y, sp.z);
      d[e].x = fminf(d[e].x, nd.x);
      d[e].y = fminf(d[e].y, nd.y);
    }
  }
}

// ---------------- radius neighbors (<=64 nearest within r) ----------------
// Single distance pass compacts candidate keys (atomic order irrelevant);
// if count <= 64 the first-pass nbr writes stand (set semantics — max-agg is
// order-independent). Overflow: rank select — rank_i = #{j: key_j < key_i}
// over broadcast LDS reads; keys unique -> ranks unique -> exact top-64 by
// (d2, idx) ascending == lax.top_k ordering with ties -> lower index.
template <int NPTS, int M>
__global__ void __launch_bounds__(256) radius_kernel(const float* __restrict__ pos,
                                                     const float* __restrict__ pos_s,
                                                     float r2,
                                                     int* __restrict__ nbr,
                                                     int* __restrict__ cnt) {
  __shared__ unsigned long long candkey[NPTS];
  __shared__ int ctr;
  const int blk = blockIdx.x;
  const int t = threadIdx.x;
  const int b = blk / M;
  const float* pb = pos + (size_t)b * NPTS * 3;
  const float cx = pos_s[(size_t)blk * 3 + 0];
  const float cy = pos_s[(size_t)blk * 3 + 1];
  const float cz = pos_s[(size_t)blk * 3 + 2];
  if (t == 0) ctr = 0;
  __syncthreads();
  for (int j = t; j < NPTS; j += 256) {
    float d2 = dist2f(pb[j * 3 + 0], pb[j * 3 + 1], pb[j * 3 + 2], cx, cy, cz);
    if (d2 <= r2) {
      int p = atomicAdd(&ctr, 1);
      candkey[p] = packMinKey(d2, j);
      if (p < KNB) nbr[(size_t)blk * KNB + p] = j;
    }
  }
  __syncthreads();
  const int c = ctr;
  if (c <= KNB) {
    if (t == 0) cnt[blk] = c;
    return;
  }
  for (int s = t; s < c; s += 256) {
    unsigned long long mykey = candkey[s];
    int rank = 0;
#pragma unroll 4
    for (int j = 0; j < c; ++j) {
      rank += (candkey[j] < mykey) ? 1 : 0;  // uniform addr -> LDS broadcast
    }
    if (rank < KNB)
      nbr[(size_t)blk * KNB + rank] = (int)(unsigned)(mykey & 0xffffffffULL);
  }
  if (t == 0) cnt[blk] = KNB;
}

// ---------------- stage 1 conv: 35 -> 64 -> 64 -> 64, max over nbrs ----------------
__global__ void __launch_bounds__(64) conv1_kernel(
    const float* __restrict__ x0, const float* __restrict__ pos,
    const float* __restrict__ pos_s, const int* __restrict__ nbr,
    const int* __restrict__ cntp,
    const float* __restrict__ w0, const float* __restrict__ b0,
    const float* __restrict__ w1, const float* __restrict__ b1,
    const float* __restrict__ w2, const float* __restrict__ b2,
    float* __restrict__ x1) {
  __shared__ float ins[35];
  __shared__ float h[64];
  const int blk = blockIdx.x;  // B*1024
  const int t = threadIdx.x;
  const int b = blk >> 10;
  const int c = cntp[blk];
  const float cx = pos_s[(size_t)blk * 3 + 0];
  const float cy = pos_s[(size_t)blk * 3 + 1];
  const float cz = pos_s[(size_t)blk * 3 + 2];
  float best = -__builtin_inff();
  for (int r = 0; r < c; ++r) {
    int j = nbr[(size_t)blk * KNB + r];
    if (t < 32) {
      ins[t] = x0[((size_t)(b * N0) + j) * 32 + t];
    } else if (t < 35) {
      float pv = pos[((size_t)(b * N0) + j) * 3 + (t - 32)];
      float cv = (t == 32) ? cx : (t == 33) ? cy : cz;
      ins[t] = pv - cv;
    }
    __syncthreads();
    float v = b0[t];
#pragma unroll
    for (int i = 0; i < 35; ++i) v = fmaf(ins[i], w0[i * 64 + t], v);
    v = fmaxf(v, 0.f);
    h[t] = v;
    __syncthreads();
    float v2 = b1[t];
#pragma unroll
    for (int i = 0; i < 64; ++i) v2 = fmaf(h[i], w1[i * 64 + t], v2);
    v2 = fmaxf(v2, 0.f);
    __syncthreads();
    h[t] = v2;
    __syncthreads();
    float v3 = b2[t];
#pragma unroll
    for (int i = 0; i < 64; ++i) v3 = fmaf(h[i], w2[i * 64 + t], v3);
    best = fmaxf(best, v3);
    __syncthreads();
  }
  x1[(size_t)blk * 64 + t] = best;
}

// ---------------- stage 2 conv: 67 -> 128 -> 128 -> 256, max over nbrs ----------------
__global__ void __launch_bounds__(256) conv2_kernel(
    const float* __restrict__ x1, const float* __restrict__ pos1,
    const float* __restrict__ pos2, const int* __restrict__ nbr,
    const int* __restrict__ cntp,
    const float* __restrict__ w0, const float* __restrict__ b0,
    const float* __restrict__ w1, const float* __restrict__ b1,
    const float* __restrict__ w2, const float* __restrict__ b2,
    float* __restrict__ x2) {
  __shared__ __attribute__((aligned(16))) float msg[64][68];
  __shared__ __attribute__((aligned(16))) float h[64][128];
  __shared__ float red[8][256];
  const int blk = blockIdx.x;  // B*256
  const int t = threadIdx.x;
  const int b = blk >> 8;
  const int c = cntp[blk];
  const float cx = pos2[(size_t)blk * 3 + 0];
  const float cy = pos2[(size_t)blk * 3 + 1];
  const float cz = pos2[(size_t)blk * 3 + 2];
  for (int idx = t; idx < 64 * 68; idx += 256) {
    int r = idx / 68;
    int k = idx - r * 68;
    float v = 0.f;
    if (r < c && k < 67) {
      int j = nbr[(size_t)blk * KNB + r];
      if (k < 64) {
        v = x1[((size_t)(b * 1024) + j) * 64 + k];
      } else {
        float pv = pos1[((size_t)(b * 1024) + j) * 3 + (k - 64)];
        v = pv - ((k == 64) ? cx : (k == 65) ? cy : cz);
      }
    }
    msg[r][k] = v;
  }
  __syncthreads();
  const int rg = t >> 5;  // 8 row-groups of 8 rows
  const int cg = t & 31;
  // L1: K=67 -> h[64][128]
  {
    float acc[8][4] = {};
    for (int i4 = 0; i4 < 16; ++i4) {
      float wv[4][4];
#pragma unroll
      for (int k = 0; k < 4; ++k) {
        float4 q = *(const float4*)&w0[(size_t)(i4 * 4 + k) * 128 + cg * 4];
        wv[k][0] = q.x; wv[k][1] = q.y; wv[k][2] = q.z; wv[k][3] = q.w;
      }
#pragma unroll
      for (int rr = 0; rr < 8; ++rr) {
        float4 aq = *(const float4*)&msg[rg * 8 + rr][i4 * 4];
        float a[4] = {aq.x, aq.y, aq.z, aq.w};
#pragma unroll
        for (int k = 0; k < 4; ++k)
#pragma unroll
          for (int cc = 0; cc < 4; ++cc)
            acc[rr][cc] = fmaf(a[k], wv[k][cc], acc[rr][cc]);
      }
    }
#pragma unroll
    for (int i = 64; i < 67; ++i) {
      float wv[4];
#pragma unroll
      for (int cc = 0; cc < 4; ++cc) wv[cc] = w0[(size_t)i * 128 + cg * 4 + cc];
#pragma unroll
      for (int rr = 0; rr < 8; ++rr) {
        float a = msg[rg * 8 + rr][i];
#pragma unroll
        for (int cc = 0; cc < 4; ++cc) acc[rr][cc] = fmaf(a, wv[cc], acc[rr][cc]);
      }
    }
#pragma unroll
    for (int rr = 0; rr < 8; ++rr)
#pragma unroll
      for (int cc = 0; cc < 4; ++cc)
        h[rg * 8 + rr][cg * 4 + cc] = fmaxf(acc[rr][cc] + b0[cg * 4 + cc], 0.f);
  }
  __syncthreads();
  // L2: K=128, in-place on h
  {
    float acc[8][4] = {};
    for (int i4 = 0; i4 < 32; ++i4) {
      float wv[4][4];
#pragma unroll
      for (int k = 0; k < 4; ++k) {
        float4 q = *(const float4*)&w1[(size_t)(i4 * 4 + k) * 128 + cg * 4];
        wv[k][0] = q.x; wv[k][1] = q.y; wv[k][2] = q.z; wv[k][3] = q.w;
      }
#pragma unroll
      for (int rr = 0; rr < 8; ++rr) {
        float4 aq = *(const float4*)&h[rg * 8 + rr][i4 * 4];
        float a[4] = {aq.x, aq.y, aq.z, aq.w};
#pragma unroll
        for (int k = 0; k < 4; ++k)
#pragma unroll
          for (int cc = 0; cc < 4; ++cc)
            acc[rr][cc] = fmaf(a[k], wv[k][cc], acc[rr][cc]);
      }
    }
    __syncthreads();  // all reads of h done before overwrite
#pragma unroll
    for (int rr = 0; rr < 8; ++rr)
#pragma unroll
      for (int cc = 0; cc < 4; ++cc)
        h[rg * 8 + rr][cg * 4 + cc] = fmaxf(acc[rr][cc] + b1[cg * 4 + cc], 0.f);
  }
  __syncthreads();
  // L3: K=128 -> 64x256, then masked max over rows
  {
    float acc[8][8] = {};
    for (int i4 = 0; i4 < 32; ++i4) {
      float wv[4][8];
#pragma unroll
      for (int k = 0; k < 4; ++k) {
        float4 q0 = *(const float4*)&w2[(size_t)(i4 * 4 + k) * 256 + cg * 8];
        float4 q1 = *(const float4*)&w2[(size_t)(i4 * 4 + k) * 256 + cg * 8 + 4];
        wv[k][0] = q0.x; wv[k][1] = q0.y; wv[k][2] = q0.z; wv[k][3] = q0.w;
        wv[k][4] = q1.x; wv[k][5] = q1.y; wv[k][6] = q1.z; wv[k][7] = q1.w;
      }
#pragma unroll
      for (int rr = 0; rr < 8; ++rr) {
        float4 aq = *(const float4*)&h[rg * 8 + rr][i4 * 4];
        float a[4] = {aq.x, aq.y, aq.z, aq.w};
#pragma unroll
        for (int k = 0; k < 4; ++k)
#pragma unroll
          for (int cc = 0; cc < 8; ++cc)
            acc[rr][cc] = fmaf(a[k], wv[k][cc], acc[rr][cc]);
      }
    }
    float mx[8];
#pragma unroll
    for (int cc = 0; cc < 8; ++cc) mx[cc] = -__builtin_inff();
#pragma unroll
    for (int rr = 0; rr < 8; ++rr) {
      if (rg * 8 + rr < c) {
#pragma unroll
        for (int cc = 0; cc < 8; ++cc)
          mx[cc] = fmaxf(mx[cc], acc[rr][cc] + b2[cg * 8 + cc]);
      }
    }
#pragma unroll
    for (int cc = 0; cc < 8; ++cc) red[rg][cg * 8 + cc] = mx[cc];
  }
  __syncthreads();
  {
    float v = red[0][t];
#pragma unroll
    for (int g = 1; g < 8; ++g) v = fmaxf(v, red[g][t]);
    x2[(size_t)blk * 256 + t] = v;
  }
}

// ---------------- stage 3 conv: 259 -> 256 -> 512 -> 512, max over nbrs ----------------
__global__ void __launch_bounds__(256) conv3_kernel(
    const float* __restrict__ x2, const float* __restrict__ pos2,
    const float* __restrict__ pos3, const int* __restrict__ nbr,
    const int* __restrict__ cntp,
    const float* __restrict__ w0, const float* __restrict__ b0,
    const float* __restrict__ w1, const float* __restrict__ b1,
    const float* __restrict__ w2, const float* __restrict__ b2,
    float* __restrict__ out) {
  __shared__ __attribute__((aligned(16))) float msg[16][260];
  __shared__ __attribute__((aligned(16))) float h[16][512];
  __shared__ float red[4][512];
  __shared__ float omax[512];
  const int blk = blockIdx.x;  // B*64
  const int t = threadIdx.x;
  const int b = blk >> 6;
  const int c = cntp[blk];
  const float cx = pos3[(size_t)blk * 3 + 0];
  const float cy = pos3[(size_t)blk * 3 + 1];
  const float cz = pos3[(size_t)blk * 3 + 2];
  omax[t] = -__builtin_inff();
  omax[t + 256] = -__builtin_inff();
  const int rg = t >> 6;  // 4 row-groups of 4 rows
  const int cg = t & 63;
  __syncthreads();
  for (int ch = 0; ch < 4; ++ch) {
    if (ch * 16 >= c) break;
    for (int idx = t; idx < 16 * 260; idx += 256) {
      int r = idx / 260;
      int k = idx - r * 260;
      int rglob = ch * 16 + r;
      float v = 0.f;
      if (rglob < c && k < 259) {
        int j = nbr[(size_t)blk * KNB + rglob];
        if (k < 256) {
          v = x2[((size_t)(b * 256) + j) * 256 + k];
        } else {
          float pv = pos2[((size_t)(b * 256) + j) * 3 + (k - 256)];
          v = pv - ((k == 256) ? cx : (k == 257) ? cy : cz);
        }
      }
      msg[r][k] = v;
    }
    __syncthreads();
    // L1: 16x256, K=259
    {
      float acc[4][4] = {};
      for (int i4 = 0; i4 < 64; ++i4) {
        float wv[4][4];
#pragma unroll
        for (int k = 0; k < 4; ++k) {
          float4 q = *(const float4*)&w0[(size_t)(i4 * 4 + k) * 256 + cg * 4];
          wv[k][0] = q.x; wv[k][1] = q.y; wv[k][2] = q.z; wv[k][3] = q.w;
        }
#pragma unroll
        for (int rr = 0; rr < 4; ++rr) {
          float4 aq = *(const float4*)&msg[rg * 4 + rr][i4 * 4];
          float a[4] = {aq.x, aq.y, aq.z, aq.w};
#pragma unroll
          for (int k = 0; k < 4; ++k)
#pragma unroll
            for (int cc = 0; cc < 4; ++cc)
              acc[rr][cc] = fmaf(a[k], wv[k][cc], acc[rr][cc]);
        }
      }
#pragma unroll
      for (int i = 256; i < 259; ++i) {
        float wv[4];
#pragma unroll
        for (int cc = 0; cc < 4; ++cc) wv[cc] = w0[(size_t)i * 256 + cg * 4 + cc];
#pragma unroll
        for (int rr = 0; rr < 4; ++rr) {
          float a = msg[rg * 4 + rr][i];
#pragma unroll
          for (int cc = 0; cc < 4; ++cc) acc[rr][cc] = fmaf(a, wv[cc], acc[rr][cc]);
        }
      }
#pragma unroll
      for (int rr = 0; rr < 4; ++rr)
#pragma unroll
        for (int cc = 0; cc < 4; ++cc)
          h[rg * 4 + rr][cg * 4 + cc] = fmaxf(acc[rr][cc] + b0[cg * 4 + cc], 0.f);
    }
    __syncthreads();
    // L2: 16x512, K=256, in-place on h (read cols 0..255, write 0..511)
    {
      float acc[4][8] = {};
      for (int i4 = 0; i4 < 64; ++i4) {
        float wv[4][8];
#pragma unroll
        for (int k = 0; k < 4; ++k) {
          float4 q0 = *(const float4*)&w1[(size_t)(i4 * 4 + k) * 512 + cg * 8];
          float4 q1 = *(const float4*)&w1[(size_t)(i4 * 4 + k) * 512 + cg * 8 + 4];
          wv[k][0] = q0.x; wv[k][1] = q0.y; wv[k][2] = q0.z; wv[k][3] = q0.w;
          wv[k][4] = q1.x; wv[k][5] = q1.y; wv[k][6] = q1.z; wv[k][7] = q1.w;
        }
#pragma unroll
        for (int rr = 0; rr < 4; ++rr) {
          float4 aq = *(const float4*)&h[rg * 4 + rr][i4 * 4];
          float a[4] = {aq.x, aq.y, aq.z, aq.w};
#pragma unroll
          for (int k = 0; k < 4; ++k)
#pragma unroll
            for (int cc = 0; cc < 8; ++cc)
              acc[rr][cc] = fmaf(a[k], wv[k][cc], acc[rr][cc]);
        }
      }
      __syncthreads();
#pragma unroll
      for (int rr = 0; rr < 4; ++rr)
#pragma unroll
        for (int cc = 0; cc < 8; ++cc)
          h[rg * 4 + rr][cg * 8 + cc] = fmaxf(acc[rr][cc] + b1[cg * 8 + cc], 0.f);
    }
    __syncthreads();
    // L3: 16x512, K=512, masked max
    {
      float acc[4][8] = {};
      for (int i4 = 0; i4 < 128; ++i4) {
        float wv[4][8];
#pragma unroll
        for (int k = 0; k < 4; ++k) {
          float4 q0 = *(const float4*)&w2[(size_t)(i4 * 4 + k) * 512 + cg * 8];
          float4 q1 = *(const float4*)&w2[(size_t)(i4 * 4 + k) * 512 + cg * 8 + 4];
          wv[k][0] = q0.x; wv[k][1] = q0.y; wv[k][2] = q0.z; wv[k][3] = q0.w;
          wv[k][4] = q1.x; wv[k][5] = q1.y; wv[k][6] = q1.z; wv[k][7] = q1.w;
        }
#pragma unroll
        for (int rr = 0; rr < 4; ++rr) {
          float4 aq = *(const float4*)&h[rg * 4 + rr][i4 * 4];
          float a[4] = {aq.x, aq.y, aq.z, aq.w};
#pragma unroll
          for (int k = 0; k < 4; ++k)
#pragma unroll
            for (int cc = 0; cc < 8; ++cc)
              acc[rr][cc] = fmaf(a[k], wv[k][cc], acc[rr][cc]);
        }
      }
      float mx[8];
#pragma unroll
      for (int cc = 0; cc < 8; ++cc) mx[cc] = -__builtin_inff();
#pragma unroll
      for (int rr = 0; rr < 4; ++rr) {
        if (ch * 16 + rg * 4 + rr < c) {
#pragma unroll
          for (int cc = 0; cc < 8; ++cc)
            mx[cc] = fmaxf(mx[cc], acc[rr][cc] + b2[cg * 8 + cc]);
        }
      }
#pragma unroll
      for (int cc = 0; cc < 8; ++cc) red[rg][cg * 8 + cc] = mx[cc];
    }
    __syncthreads();
    for (int k = t; k < 512; k += 256) {
      float v = omax[k];
#pragma unroll
      for (int g = 0; g < 4; ++g) v = fmaxf(v, red[g][k]);
      omax[k] = v;
    }
    __syncthreads();
  }
  out[(size_t)blk * 512 + t] = omax[t];
  out[(size_t)blk * 512 + t + 256] = omax[t + 256];
}

extern "C" void kernel_launch(void* const* d_in, const int* in_sizes, int n_in,
                              void* d_out, int out_size, void* d_ws, size_t ws_size,
                              hipStream_t stream) {
  const int* feat = (const int*)d_in[0];
  const float* pos = (const float*)d_in[1];
  const float* emb = (const float*)d_in[2];
  const float* pid = (const float*)d_in[3];
  const float* s1w0 = (const float*)d_in[4];
  const float* s1b0 = (const float*)d_in[5];
  const float* s1w1 = (const float*)d_in[6];
  const float* s1b1 = (const float*)d_in[7];
  const float* s1w2 = (const float*)d_in[8];
  const float* s1b2 = (const float*)d_in[9];
  const float* s2w0 = (const float*)d_in[10];
  const float* s2b0 = (const float*)d_in[11];
  const float* s2w1 = (const float*)d_in[12];
  const float* s2b1 = (const float*)d_in[13];
  const float* s2w2 = (const float*)d_in[14];
  const float* s2b2 = (const float*)d_in[15];
  const float* s3w0 = (const float*)d_in[16];
  const float* s3b0 = (const float*)d_in[17];
  const float* s3w1 = (const float*)d_in[18];
  const float* s3b1 = (const float*)d_in[19];
  const float* s3w2 = (const float*)d_in[20];
  const float* s3b2 = (const float*)d_in[21];
  (void)in_sizes; (void)n_in; (void)out_size; (void)ws_size;

  char* ws = (char*)d_ws;
  size_t off = 0;
  auto alloc = [&](size_t nbytes) {
    void* p = ws + off;
    off = (off + nbytes + 255) & ~(size_t)255;
    return p;
  };
  float* x0 = (float*)alloc((size_t)B * N0 * 32 * 4);
  float* pos1 = (float*)alloc((size_t)B * 1024 * 3 * 4);
  int* nbr1 = (int*)alloc((size_t)B * 1024 * KNB * 4);
  int* cnt1 = (int*)alloc((size_t)B * 1024 * 4);
  float* x1 = (float*)alloc((size_t)B * 1024 * 64 * 4);
  float* pos2 = (float*)alloc((size_t)B * 256 * 3 * 4);
  int* nbr2 = (int*)alloc((size_t)B * 256 * KNB * 4);
  int* cnt2 = (int*)alloc((size_t)B * 256 * 4);
  float* x2 = (float*)alloc((size_t)B * 256 * 256 * 4);
  int* nbr3 = (int*)alloc((size_t)B * 64 * KNB * 4);
  int* cnt3 = (int*)alloc((size_t)B * 64 * 4);

  float* xout = (float*)d_out;                 // (B,64,512)
  float* pos3 = xout + (size_t)B * 64 * 512;   // (B,64,3)

  const float r2a = (float)(0.05 * 0.05);
  const float r2b = (float)(0.3 * 0.3);
  const float r2c = (float)(0.5 * 0.5);

  x0_kernel<<<(B * N0 * 32 + 255) / 256, 256, 0, stream>>>(feat, emb, pid, x0);

  fps_kernel<4096, 1024, 256><<<B, 256, 0, stream>>>(pos, pos1);
  radius_kernel<4096, 1024><<<B * 1024, 256, 0, stream>>>(pos, pos1, r2a, nbr1, cnt1);
  conv1_kernel<<<B * 1024, 64, 0, stream>>>(x0, pos, pos1, nbr1, cnt1,
                                            s1w0, s1b0, s1w1, s1b1, s1w2, s1b2, x1);

  fps_kernel<1024, 256, 256><<<B, 256, 0, stream>>>(pos1, pos2);
  radius_kernel<1024, 256><<<B * 256, 256, 0, stream>>>(pos1, pos2, r2b, nbr2, cnt2);
  conv2_kernel<<<B * 256, 256, 0, stream>>>(x1, pos1, pos2, nbr2, cnt2,
                                            s2w0, s2b0, s2w1, s2b1, s2w2, s2b2, x2);

  fps_kernel<256, 64, 64><<<B, 64, 0, stream>>>(pos2, pos3);
  radius_kernel<256, 64><<<B * 64, 256, 0, stream>>>(pos2, pos3, r2c, nbr3, cnt3);
  conv3_kernel<<<B * 64, 256, 0, stream>>>(x2, pos2, pos3, nbr3, cnt3,
                                           s3w0, s3b0, s3w1, s3b1, s3w2, s3b2, xout);
}